// Round 8
// baseline (201.197 us; speedup 1.0000x reference)
//
#include <hip/hip_runtime.h>
#include <stdint.h>

#define EPSF 1e-6f

typedef unsigned short u16;
typedef __attribute__((ext_vector_type(8))) u16 u16x8;
typedef __attribute__((ext_vector_type(8))) __bf16 bf16x8;
typedef __attribute__((ext_vector_type(4))) float f32x4;

static constexpr int NBI = 128, NBT = 128, KI = 36, LC = 50, DD = 1024;
static constexpr int NEL = KI * LC;   // 1800
static constexpr int GM  = NBI * KI;  // 4608
static constexpr int GN  = NBT * LC;  // 6400
static constexpr int BK = 64;
static constexpr int KT = DD / BK;    // 16

static __device__ __forceinline__ u16 f2bf(float f) {  // RNE
  uint32_t u = __float_as_uint(f);
  u += 0x7fffu + ((u >> 16) & 1u);
  return (u16)(u >> 16);
}
static __device__ __forceinline__ float bf2f(u16 h) {
  return __uint_as_float((uint32_t)h << 16);
}

typedef __attribute__((address_space(1))) void gv_t;
typedef __attribute__((address_space(3))) void lv_t;
static __device__ __forceinline__ void gload16(const void* g, void* l) {
  __builtin_amdgcn_global_load_lds((const gv_t*)g, (lv_t*)l, 16, 0, 0);
}

// ---------------- kernel H: header = prefix sums of live rows + padded dims --------
// h[0]=Mlive h[1]=Mt(128-tiles) h[2]=Nlive h[3]=Nt h[4]=Npad ; h[8+i]=aoff ; h[136+t]=boff
__global__ void hcam_hdr(const int* __restrict__ ilen, const int* __restrict__ clen,
                         int* __restrict__ h) {
  if (threadIdx.x == 0 && blockIdx.x == 0) {
    int s = 0;
    for (int i = 0; i < NBI; ++i) { h[8 + i] = s; s += ilen[i]; }
    h[0] = s; h[1] = (s + 127) >> 7;
    int s2 = 0;
    for (int t = 0; t < NBT; ++t) { h[136 + t] = s2; s2 += clen[t]; }
    h[2] = s2; h[3] = (s2 + 127) >> 7; h[4] = h[3] << 7;
  }
}

// ---------------- kernel 0: normalize live rows, cast bf16, write COMPACTED --------
__global__ __launch_bounds__(256) void hcam_normcast_c(
    const float* __restrict__ imgs, const float* __restrict__ caps,
    const int* __restrict__ ilen, const int* __restrict__ clen,
    const int* __restrict__ h, u16* __restrict__ A, u16* __restrict__ B) {
  int r = blockIdx.x;
  const float* src; u16* dst;
  if (r < GM) {
    int i = r / KI, k = r - i * KI;
    if (k >= ilen[i]) return;                    // dead row: skip entirely
    src = imgs + (size_t)r * DD;
    dst = A + (size_t)(h[8 + i] + k) * DD;
  } else {
    int rb = r - GM;
    int t = rb / LC, l = rb - t * LC;
    if (l >= clen[t]) return;
    src = caps + (size_t)rb * DD;
    dst = B + (size_t)(h[136 + t] + l) * DD;
  }
  int tid = threadIdx.x;
  float4 v = *(const float4*)(src + tid * 4);
  v.x += EPSF; v.y += EPSF; v.z += EPSF; v.w += EPSF;
  float ss = v.x * v.x + v.y * v.y + v.z * v.z + v.w * v.w;
  #pragma unroll
  for (int m = 32; m; m >>= 1) ss += __shfl_xor(ss, m);
  __shared__ float wsum[4];
  if ((tid & 63) == 0) wsum[tid >> 6] = ss;
  __syncthreads();
  float inv = 1.0f / sqrtf(wsum[0] + wsum[1] + wsum[2] + wsum[3]);
  ushort4 o = make_ushort4(f2bf(v.x * inv), f2bf(v.y * inv), f2bf(v.z * inv), f2bf(v.w * inv));
  *(ushort4*)(dst + tid * 4) = o;
}

// ---------------- kernel 1: C = A'*B'^T over compacted dims, m97-style 128x128 -----
// 256 thr = 4 waves (2x2), 64x64 out each. Single 32KB LDS buffer pair; per tile:
// stage (8x gload16/thread-total) -> vmcnt(0) -> barrier -> 16 ds_read + 32 MFMA
// per wave (0.5 KB/MFMA) -> barrier. ~4 blocks/CU (32KB LDS, <=128 VGPR) so the
// drain stall overlaps ACROSS blocks (the piece every 1-block/CU 256^2 variant
// lacked). Swizzle rule #21: inverse-swizzled global source, swizzled ds_read.
// Grid = worst-case 36x50 = 1800 (1800%8==0 -> simple XCD swizzle); dead tiles
// exit on header. C stride = Npad (runtime), fp16.
__global__ __launch_bounds__(256, 4) void hcam_gemm128(
    const u16* __restrict__ A, const u16* __restrict__ B, _Float16* __restrict__ C,
    const int* __restrict__ h) {
  const int Mt = h[1], Nt = h[3], Npad = h[4];
  const int orig = blockIdx.x;
  const int wg = (orig & 7) * 225 + (orig >> 3);   // 1800/8 = 225, bijective
  const int bm = wg % 36, bn = wg / 36;
  if (bm >= Mt || bn >= Nt) return;
  __shared__ u16 As[128 * BK];
  __shared__ u16 Bs[128 * BK];

  const int tid = threadIdx.x, lane = tid & 63, w = tid >> 6;
  const int wm = w >> 1, wn = w & 1;               // 2x2 waves
  const u16* Ag = A + (size_t)(bm * 128) * DD;
  const u16* Bg = B + (size_t)(bn * 128) * DD;

  const int srow = tid >> 3;                       // 0..31
  const int sc16 = (tid & 7) ^ (srow & 7);         // inverse swizzle (row&7 == srow&7)

  f32x4 acc[4][4];
  #pragma unroll
  for (int i = 0; i < 4; ++i)
    #pragma unroll
    for (int j = 0; j < 4; ++j) acc[i][j] = (f32x4){0.f, 0.f, 0.f, 0.f};

  const int fr = lane & 15, g4 = lane >> 4;

  #pragma unroll 1
  for (int kt = 0; kt < KT; ++kt) {
    const int kb = kt * BK;
    #pragma unroll
    for (int j = 0; j < 4; ++j) {                  // 4 issues x 32 rows each
      const int row = j * 32 + srow;
      const size_t gof = (size_t)row * DD + kb + sc16 * 8;
      gload16(Ag + gof, As + (j * 32 + w * 8) * BK);
      gload16(Bg + gof, Bs + (j * 32 + w * 8) * BK);
    }
    asm volatile("s_waitcnt vmcnt(0)" ::: "memory");
    __builtin_amdgcn_s_barrier();

    bf16x8 af[4][2], bfv[4][2];
    #pragma unroll
    for (int k2 = 0; k2 < 2; ++k2) {
      const int cs = (((k2 << 2) + g4) ^ (fr & 7)) << 3;
      #pragma unroll
      for (int mi = 0; mi < 4; ++mi)
        af[mi][k2] = __builtin_bit_cast(bf16x8,
            *(const u16x8*)(As + (wm * 64 + mi * 16 + fr) * BK + cs));
      #pragma unroll
      for (int ni = 0; ni < 4; ++ni)
        bfv[ni][k2] = __builtin_bit_cast(bf16x8,
            *(const u16x8*)(Bs + (wn * 64 + ni * 16 + fr) * BK + cs));
    }
    __builtin_amdgcn_s_setprio(1);
    #pragma unroll
    for (int k2 = 0; k2 < 2; ++k2)
      #pragma unroll
      for (int mi = 0; mi < 4; ++mi)
        #pragma unroll
        for (int ni = 0; ni < 4; ++ni)
          acc[mi][ni] = __builtin_amdgcn_mfma_f32_16x16x32_bf16(
              af[mi][k2], bfv[ni][k2], acc[mi][ni], 0, 0, 0);
    __builtin_amdgcn_s_setprio(0);
    __builtin_amdgcn_s_barrier();
  }

  // C/D layout: col = lane&15, row = (lane>>4)*4 + j (m89-verified)
  const int fc = lane & 15, fq = (lane >> 4) * 4;
  #pragma unroll
  for (int mi = 0; mi < 4; ++mi)
    #pragma unroll
    for (int ni = 0; ni < 4; ++ni) {
      const int row0 = bm * 128 + wm * 64 + mi * 16 + fq;
      const int col  = bn * 128 + wn * 64 + ni * 16 + fc;
      #pragma unroll
      for (int j = 0; j < 4; ++j)
        C[(size_t)(row0 + j) * Npad + col] = (_Float16)acc[mi][ni][j];
    }
}

// ---------------- kernel 2: wave-per-row sparsemax on COMPACTED C ------------------
// v[36]: row r, col lane (cl <= 50 < 64 -> one elem/lane/row). Dead slots -1e30
// self-exclude; the 1800 - il*cl exact zeros participate analytically (mzero).
__global__ __launch_bounds__(256) void hcam_spmax_w(
    const _Float16* __restrict__ C, const int* __restrict__ ilen,
    const int* __restrict__ clen, const int* __restrict__ h,
    float* __restrict__ out) {
  const int wid  = blockIdx.x * 4 + (threadIdx.x >> 6);
  const int lane = threadIdx.x & 63;
  const int i = wid >> 7, t = wid & 127;
  const int il = ilen[i], cl = clen[t];
  const int Npad = h[4];
  const _Float16* base = C + (size_t)h[8 + i] * Npad + h[136 + t];

  float v[KI];
  float sum = 0.f;
  const bool lv = lane < cl;
  #pragma unroll
  for (int r = 0; r < KI; ++r) {
    float x = -1e30f;
    if (r < il && lv) { x = (float)base[(size_t)r * Npad + lane]; sum += x; }
    v[r] = x;
  }
  #pragma unroll
  for (int m = 32; m; m >>= 1) sum += __shfl_xor(sum, m);

  const float mzero = (float)(NEL - il * cl);
  float tau  = (sum - 1.0f) * (1.0f / NEL);
  float prev = (float)NEL;
  for (int it = 0; it < 32; ++it) {
    float ss = 0.f, cc = 0.f;
    #pragma unroll
    for (int r = 0; r < KI; ++r) {
      if (v[r] > tau) { ss += v[r]; cc += 1.0f; }
    }
    #pragma unroll
    for (int m = 32; m; m >>= 1) { ss += __shfl_xor(ss, m); cc += __shfl_xor(cc, m); }
    if (tau < 0.f) cc += mzero;
    if (cc == prev || cc < 1.0f) break;
    float tn = (ss - 1.0f) / cc;
    prev = cc;
    if (tn <= tau) break;
    tau = tn;
  }

  float o = 0.f;
  #pragma unroll
  for (int r = 0; r < KI; ++r) {
    float d = v[r] - tau;
    if (d > 0.f) o += v[r] * d;
  }
  #pragma unroll
  for (int m = 32; m; m >>= 1) o += __shfl_xor(o, m);
  if (lane == 0) out[wid] = o;
}

// ================= fallback path (uncompacted), unchanged ==========================
__global__ __launch_bounds__(256) void hcam_normcast(
    const float* __restrict__ imgs, const float* __restrict__ caps,
    u16* __restrict__ A, u16* __restrict__ B) {
  int r = blockIdx.x;
  const float* src; u16* dst;
  if (r < GM) { src = imgs + (size_t)r * DD;        dst = A + (size_t)r * DD; }
  else        { src = caps + (size_t)(r - GM) * DD; dst = B + (size_t)(r - GM) * DD; }
  int tid = threadIdx.x;
  float4 v = *(const float4*)(src + tid * 4);
  v.x += EPSF; v.y += EPSF; v.z += EPSF; v.w += EPSF;
  float ss = v.x * v.x + v.y * v.y + v.z * v.z + v.w * v.w;
  #pragma unroll
  for (int m = 32; m; m >>= 1) ss += __shfl_xor(ss, m);
  __shared__ float wsum[4];
  if ((tid & 63) == 0) wsum[tid >> 6] = ss;
  __syncthreads();
  float inv = 1.0f / sqrtf(wsum[0] + wsum[1] + wsum[2] + wsum[3]);
  ushort4 o = make_ushort4(f2bf(v.x * inv), f2bf(v.y * inv), f2bf(v.z * inv), f2bf(v.w * inv));
  *(ushort4*)(dst + tid * 4) = o;
}

static __device__ __forceinline__ void bred2(float& a, float& b2, int tid, float* red) {
  #pragma unroll
  for (int m = 32; m; m >>= 1) { a += __shfl_xor(a, m); b2 += __shfl_xor(b2, m); }
  __syncthreads();
  if ((tid & 63) == 0) { red[(tid >> 6) * 2] = a; red[(tid >> 6) * 2 + 1] = b2; }
  __syncthreads();
  a  = red[0] + red[2] + red[4] + red[6];
  b2 = red[1] + red[3] + red[5] + red[7];
}

static __device__ __forceinline__ void sparsemax_out(float vals[8], int tid, float* red, float* outp) {
  float s = 0.f, d = 0.f;
  #pragma unroll
  for (int r = 0; r < 8; ++r) { int p = tid + (r << 8); if (p < NEL) s += vals[r]; }
  bred2(s, d, tid, red);
  float tau  = (s - 1.0f) * (1.0f / NEL);
  float prev = (float)NEL;
  for (int it = 0; it < 64; ++it) {
    float ss = 0.f, cc = 0.f;
    #pragma unroll
    for (int r = 0; r < 8; ++r) {
      int p = tid + (r << 8);
      if (p < NEL && vals[r] > tau) { ss += vals[r]; cc += 1.0f; }
    }
    bred2(ss, cc, tid, red);
    if (cc == prev || cc < 1.0f) break;
    float tn = (ss - 1.0f) / cc;
    prev = cc;
    if (tn <= tau) break;
    tau = tn;
  }
  float o = 0.f; d = 0.f;
  #pragma unroll
  for (int r = 0; r < 8; ++r) {
    float v = vals[r], a2 = v - tau;
    if (a2 > 0.f) o += v * a2;
  }
  bred2(o, d, tid, red);
  if (tid == 0) *outp = o;
}

__global__ __launch_bounds__(256) void hcam_fused_bf(
    const u16* __restrict__ A, const u16* __restrict__ B,
    const int* __restrict__ ilen, const int* __restrict__ clen, float* __restrict__ out) {
  const int b = blockIdx.x;
  const int i = b >> 7, t = b & 127;
  const int tid = threadIdx.x;
  const int il = ilen[i], cl = clen[t];
  float vals[8];
  #pragma unroll
  for (int r = 0; r < 8; ++r) {
    int p = tid + (r << 8);
    float v = 0.f;
    if (p < NEL) {
      int k = p / LC, l = p - k * LC;
      if (k < il && l < cl) {
        const u16* ar = A + (size_t)(i * KI + k) * DD;
        const u16* br = B + (size_t)(t * LC + l) * DD;
        float s = 0.f;
        for (int dd = 0; dd < DD; dd += 8) {
          u16x8 av = *(const u16x8*)(ar + dd);
          u16x8 bv = *(const u16x8*)(br + dd);
          #pragma unroll
          for (int q = 0; q < 8; ++q) s += bf2f(av[q]) * bf2f(bv[q]);
        }
        v = s;
      }
    }
    vals[r] = v;
  }
  __shared__ float red[8];
  sparsemax_out(vals, tid, red, &out[b]);
}

__global__ __launch_bounds__(256) void hcam_fused_raw(
    const float* __restrict__ imgs, const float* __restrict__ caps,
    const int* __restrict__ ilen, const int* __restrict__ clen, float* __restrict__ out) {
  const int b = blockIdx.x;
  const int i = b >> 7, t = b & 127;
  const int tid = threadIdx.x;
  const int w = tid >> 6, lane = tid & 63;
  __shared__ float inv[KI + LC];
  for (int row = w; row < KI + LC; row += 4) {
    const float* src = (row < KI) ? imgs + (size_t)(i * KI + row) * DD
                                  : caps + (size_t)(t * LC + (row - KI)) * DD;
    float ss = 0.f;
    for (int e = lane; e < DD; e += 64) { float x = src[e] + EPSF; ss += x * x; }
    #pragma unroll
    for (int m = 32; m; m >>= 1) ss += __shfl_xor(ss, m);
    if (lane == 0) inv[row] = 1.0f / sqrtf(ss);
  }
  __syncthreads();
  const int il = ilen[i], cl = clen[t];
  float vals[8];
  #pragma unroll
  for (int r = 0; r < 8; ++r) {
    int p = tid + (r << 8);
    float v = 0.f;
    if (p < NEL) {
      int k = p / LC, l = p - k * LC;
      if (k < il && l < cl) {
        const float* ar = imgs + (size_t)(i * KI + k) * DD;
        const float* br = caps + (size_t)(t * LC + l) * DD;
        float s = 0.f;
        for (int dd = 0; dd < DD; dd += 4) {
          float4 a4 = *(const float4*)(ar + dd);
          float4 b4 = *(const float4*)(br + dd);
          s += (a4.x + EPSF) * (b4.x + EPSF) + (a4.y + EPSF) * (b4.y + EPSF)
             + (a4.z + EPSF) * (b4.z + EPSF) + (a4.w + EPSF) * (b4.w + EPSF);
        }
        v = s * inv[k] * inv[KI + l];
      }
    }
    vals[r] = v;
  }
  __shared__ float red[8];
  sparsemax_out(vals, tid, red, &out[b]);
}

extern "C" void kernel_launch(void* const* d_in, const int* in_sizes, int n_in,
                              void* d_out, int out_size, void* d_ws, size_t ws_size,
                              hipStream_t stream) {
  (void)in_sizes; (void)n_in; (void)out_size;
  const float* imgs = (const float*)d_in[1];
  const float* caps = (const float*)d_in[3];
  const int*   ilen = (const int*)d_in[4];
  const int*   clen = (const int*)d_in[5];
  float* out = (float*)d_out;

  const size_t offA     = 4096;                                   // header first
  const size_t offB     = offA + (size_t)GM * DD * sizeof(u16);
  const size_t offC     = offB + (size_t)GN * DD * sizeof(u16);
  const size_t needFull = offC + (size_t)GM * GN * sizeof(_Float16);
  int*      hdr = (int*)d_ws;
  u16*      A = (u16*)((char*)d_ws + offA);
  u16*      B = (u16*)((char*)d_ws + offB);
  _Float16* C = (_Float16*)((char*)d_ws + offC);

  if (ws_size >= needFull) {
    hcam_hdr<<<dim3(1), dim3(64), 0, stream>>>(ilen, clen, hdr);
    hcam_normcast_c<<<dim3(GM + GN), dim3(256), 0, stream>>>(imgs, caps, ilen, clen, hdr, A, B);
    hcam_gemm128<<<dim3(36 * 50), dim3(256), 0, stream>>>(A, B, C, hdr);
    hcam_spmax_w<<<dim3(NBI * NBT / 4), dim3(256), 0, stream>>>(C, ilen, clen, hdr, out);
  } else if (ws_size >= offC) {
    hcam_normcast<<<dim3(GM + GN), dim3(256), 0, stream>>>(imgs, caps, A, B);
    hcam_fused_bf<<<dim3(NBI * NBT), dim3(256), 0, stream>>>(A, B, ilen, clen, out);
  } else {
    hcam_fused_raw<<<dim3(NBI * NBT), dim3(256), 0, stream>>>(imgs, caps, ilen, clen, out);
  }
}

// Round 9
// 137.246 us; speedup vs baseline: 1.4660x; 1.4660x over previous
//
#include <hip/hip_runtime.h>
#include <stdint.h>

#define EPSF 1e-6f

typedef unsigned short u16;
typedef __attribute__((ext_vector_type(8))) u16 u16x8;
typedef __attribute__((ext_vector_type(8))) __bf16 bf16x8;
typedef __attribute__((ext_vector_type(4))) float f32x4;

static constexpr int NBI = 128, NBT = 128, KI = 36, LC = 50, DD = 1024;
static constexpr int NEL = KI * LC;   // 1800
static constexpr int GM  = NBI * KI;  // 4608
static constexpr int GN  = NBT * LC;  // 6400
static constexpr int BM = 128, BN = 128, BK = 32;
static constexpr int KT = DD / BK;    // 32
static constexpr int MT = GM / BM;    // 36
static constexpr int NT = GN / BN;    // 50
static constexpr int TBA = BM * BK;   // 4096 elems = 8KB per buffer per matrix

static __device__ __forceinline__ u16 f2bf(float f) {  // RNE
  uint32_t u = __float_as_uint(f);
  u += 0x7fffu + ((u >> 16) & 1u);
  return (u16)(u >> 16);
}
static __device__ __forceinline__ float bf2f(u16 h) {
  return __uint_as_float((uint32_t)h << 16);
}

typedef __attribute__((address_space(1))) void gv_t;
typedef __attribute__((address_space(3))) void lv_t;
static __device__ __forceinline__ void gload16(const void* g, void* l) {
  __builtin_amdgcn_global_load_lds((const gv_t*)g, (lv_t*)l, 16, 0, 0);
}

// ---------------- kernel 0: add EPS, L2-normalize rows, cast to bf16 ----------------
__global__ __launch_bounds__(256) void hcam_normcast(
    const float* __restrict__ imgs, const float* __restrict__ caps,
    u16* __restrict__ A, u16* __restrict__ B) {
  int r = blockIdx.x;
  const float* src; u16* dst;
  if (r < GM) { src = imgs + (size_t)r * DD;        dst = A + (size_t)r * DD; }
  else        { src = caps + (size_t)(r - GM) * DD; dst = B + (size_t)(r - GM) * DD; }
  int tid = threadIdx.x;
  float4 v = *(const float4*)(src + tid * 4);
  v.x += EPSF; v.y += EPSF; v.z += EPSF; v.w += EPSF;
  float ss = v.x * v.x + v.y * v.y + v.z * v.z + v.w * v.w;
  #pragma unroll
  for (int m = 32; m; m >>= 1) ss += __shfl_xor(ss, m);
  __shared__ float wsum[4];
  if ((tid & 63) == 0) wsum[tid >> 6] = ss;
  __syncthreads();
  float inv = 1.0f / sqrtf(wsum[0] + wsum[1] + wsum[2] + wsum[3]);
  ushort4 o = make_ushort4(f2bf(v.x * inv), f2bf(v.y * inv), f2bf(v.z * inv), f2bf(v.w * inv));
  *(ushort4*)(dst + tid * 4) = o;
}

// ---------------- kernel 1: C = A*B^T, 128x128 tile, BK=32, dbuf, 4 blocks/CU ------
// Occupancy fix: 32KB LDS/block + <=128 VGPR (launch_bounds(256,4)) -> 4 blocks/CU
// = 4 waves/SIMD from INDEPENDENT blocks, so one block's vmcnt/barrier drain
// overlaps another's MFMA (the piece all 1-block/CU variants lacked).
// Schedule = R6's proven counted-vmcnt 2-barrier loop. BK=32 swizzle:
// physical col4 = logical c4 ^ ((row>>1)&3) -> 2-way bank alias (free, m136);
// staged via inverse-swizzled global source (rule #21), read back with same XOR.
__global__ __launch_bounds__(256, 4) void hcam_gemm128d(
    const u16* __restrict__ A, const u16* __restrict__ B, _Float16* __restrict__ C) {
  __shared__ u16 As[2 * TBA];
  __shared__ u16 Bs[2 * TBA];

  const int orig = blockIdx.x;                 // 1800 wgs, 1800%8==0
  const int wg = (orig & 7) * 225 + (orig >> 3);
  const int bm = wg % MT, bn = wg / MT;

  const int tid = threadIdx.x, lane = tid & 63, w = tid >> 6;
  const int wm = w >> 1, wn = w & 1;           // 2x2 waves, 64x64 out each
  const u16* Ag = A + (size_t)(bm * BM) * DD;
  const u16* Bg = B + (size_t)(bn * BN) * DD;

  // staging: row = j*64 + (tid>>2), physical col4 = tid&3; logical source col4
  // = (tid&3) ^ ((row>>1)&3) = (tid&3) ^ ((tid>>3)&3)  (j*64 doesn't affect bits)
  const int sc4 = (tid & 3) ^ ((tid >> 3) & 3);
  const int srow = tid >> 2;                   // 0..63

  // stage one matrix tile (128 rows x 32 k) = 2 gload16/thread
  auto stage = [&](const u16* g, u16* lds, int kt) {
    #pragma unroll
    for (int j = 0; j < 2; ++j) {
      int row = j * 64 + srow;
      gload16(g + (size_t)row * DD + kt * BK + sc4 * 8,
              lds + (j * 64 + w * 16) * BK);
    }
  };

  f32x4 acc[4][4];
  #pragma unroll
  for (int i = 0; i < 4; ++i)
    #pragma unroll
    for (int j = 0; j < 4; ++j) acc[i][j] = (f32x4){0.f, 0.f, 0.f, 0.f};

  const int fr = lane & 15, g4 = lane >> 4;
  const int cs = ((g4 ^ ((fr >> 1) & 3)) << 3);   // swizzled read col (elems)

  // one K-tile: 8 ds_read_b128 + 16 MFMA per wave; optional mid-tile B(t+1) stage
  auto ktile_compute = [&](const u16* as_c, const u16* bs_c, bool st, u16* bs_n, int tn) {
    bf16x8 af[4], bfv[4];
    #pragma unroll
    for (int mi = 0; mi < 4; ++mi)
      af[mi] = __builtin_bit_cast(bf16x8,
          *(const u16x8*)(as_c + (wm * 64 + mi * 16 + fr) * BK + cs));
    #pragma unroll
    for (int ni = 0; ni < 4; ++ni)
      bfv[ni] = __builtin_bit_cast(bf16x8,
          *(const u16x8*)(bs_c + (wn * 64 + ni * 16 + fr) * BK + cs));
    if (st) stage(Bg, bs_n, tn);
    __builtin_amdgcn_s_setprio(1);
    #pragma unroll
    for (int mi = 0; mi < 4; ++mi)
      #pragma unroll
      for (int ni = 0; ni < 4; ++ni)
        acc[mi][ni] = __builtin_amdgcn_mfma_f32_16x16x32_bf16(
            af[mi], bfv[ni], acc[mi][ni], 0, 0, 0);
    __builtin_amdgcn_s_setprio(0);
  };

  // queue invariant at entry(t): oldest->newest = [A(t)(2), B(t)(2)];
  // stage A(t+1) (+2) then vmcnt(2) -> tile t fully landed, A(t+1) in flight.
  auto tile = [&](int t, const u16* as_c, const u16* bs_c, u16* as_n, u16* bs_n) {
    const int tn = t + 1;
    if (tn < KT) {
      stage(Ag, as_n, tn);
      asm volatile("s_waitcnt vmcnt(2)" ::: "memory");
    } else {
      asm volatile("s_waitcnt vmcnt(0)" ::: "memory");
    }
    __builtin_amdgcn_s_barrier();                 // tile-ready
    __builtin_amdgcn_sched_barrier(0);
    ktile_compute(as_c, bs_c, tn < KT, bs_n, tn);
    __builtin_amdgcn_s_barrier();                 // reads of cur done
    __builtin_amdgcn_sched_barrier(0);
  };

  // prologue: A(0),B(0),A(1) = 6 loads -> vmcnt(2): tile 0 landed
  stage(Ag, As, 0); stage(Bg, Bs, 0);
  stage(Ag, As + TBA, 1);
  asm volatile("s_waitcnt vmcnt(2)" ::: "memory");
  __builtin_amdgcn_s_barrier();
  __builtin_amdgcn_sched_barrier(0);
  ktile_compute(As, Bs, true, Bs + TBA, 1);       // tile 0, stage B(1) mid-tile
  __builtin_amdgcn_s_barrier();
  __builtin_amdgcn_sched_barrier(0);

  #pragma unroll 1
  for (int tp = 1; tp + 1 < KT; tp += 2) {
    tile(tp,     As + TBA, Bs + TBA, As,       Bs);
    tile(tp + 1, As,       Bs,       As + TBA, Bs + TBA);
  }
  tile(KT - 1, As + TBA, Bs + TBA, As, Bs);       // tile 31 (KT=32: loop does 1..30)

  // C/D layout: col = lane&15, row = (lane>>4)*4 + j (m89-verified)
  const int fc = lane & 15, fq = (lane >> 4) * 4;
  #pragma unroll
  for (int mi = 0; mi < 4; ++mi)
    #pragma unroll
    for (int ni = 0; ni < 4; ++ni) {
      const int row0 = bm * BM + wm * 64 + mi * 16 + fq;
      const int col  = bn * BN + wn * 64 + ni * 16 + fc;
      #pragma unroll
      for (int j = 0; j < 4; ++j)
        C[(size_t)(row0 + j) * GN + col] = (_Float16)acc[mi][ni][j];
    }
}

// ---------------- kernel 2: wave-per-row sparsemax + weighted sum (fp16 C) ---------
static constexpr int RPT = (NEL + 63) / 64;   // 29

__global__ __launch_bounds__(256) void hcam_spmax_w(
    const _Float16* __restrict__ C, const int* __restrict__ ilen, const int* __restrict__ clen,
    float* __restrict__ out) {
  const int wid  = blockIdx.x * 4 + (threadIdx.x >> 6);
  const int lane = threadIdx.x & 63;
  const int i = wid >> 7, t = wid & 127;
  const int il = ilen[i], cl = clen[t];
  const _Float16* base = C + (size_t)i * KI * GN + t * LC;

  float v[RPT];
  float sum = 0.f;
  #pragma unroll
  for (int r = 0; r < RPT; ++r) {
    int p = lane + (r << 6);
    float x = -1e30f;
    if (p < NEL) {
      int k = p / LC, l = p - k * LC;
      if (k < il && l < cl) { x = (float)base[(size_t)k * GN + l]; sum += x; }
    }
    v[r] = x;
  }
  #pragma unroll
  for (int m = 32; m; m >>= 1) sum += __shfl_xor(sum, m);

  const float mzero = (float)(NEL - il * cl);
  float tau  = (sum - 1.0f) * (1.0f / NEL);
  float prev = (float)NEL;
  for (int it = 0; it < 32; ++it) {
    float ss = 0.f, cc = 0.f;
    #pragma unroll
    for (int r = 0; r < RPT; ++r) {
      if (v[r] > tau) { ss += v[r]; cc += 1.0f; }
    }
    #pragma unroll
    for (int m = 32; m; m >>= 1) { ss += __shfl_xor(ss, m); cc += __shfl_xor(cc, m); }
    if (tau < 0.f) cc += mzero;
    if (cc == prev || cc < 1.0f) break;
    float tn = (ss - 1.0f) / cc;
    prev = cc;
    if (tn <= tau) break;
    tau = tn;
  }

  float o = 0.f;
  #pragma unroll
  for (int r = 0; r < RPT; ++r) {
    float d = v[r] - tau;
    if (d > 0.f) o += v[r] * d;
  }
  #pragma unroll
  for (int m = 32; m; m >>= 1) o += __shfl_xor(o, m);
  if (lane == 0) out[wid] = o;
}

// ================= fallback path, unchanged ==========================
static __device__ __forceinline__ void bred2(float& a, float& b2, int tid, float* red) {
  #pragma unroll
  for (int m = 32; m; m >>= 1) { a += __shfl_xor(a, m); b2 += __shfl_xor(b2, m); }
  __syncthreads();
  if ((tid & 63) == 0) { red[(tid >> 6) * 2] = a; red[(tid >> 6) * 2 + 1] = b2; }
  __syncthreads();
  a  = red[0] + red[2] + red[4] + red[6];
  b2 = red[1] + red[3] + red[5] + red[7];
}

static __device__ __forceinline__ void sparsemax_out(float vals[8], int tid, float* red, float* outp) {
  float s = 0.f, d = 0.f;
  #pragma unroll
  for (int r = 0; r < 8; ++r) { int p = tid + (r << 8); if (p < NEL) s += vals[r]; }
  bred2(s, d, tid, red);
  float tau  = (s - 1.0f) * (1.0f / NEL);
  float prev = (float)NEL;
  for (int it = 0; it < 64; ++it) {
    float ss = 0.f, cc = 0.f;
    #pragma unroll
    for (int r = 0; r < 8; ++r) {
      int p = tid + (r << 8);
      if (p < NEL && vals[r] > tau) { ss += vals[r]; cc += 1.0f; }
    }
    bred2(ss, cc, tid, red);
    if (cc == prev || cc < 1.0f) break;
    float tn = (ss - 1.0f) / cc;
    prev = cc;
    if (tn <= tau) break;
    tau = tn;
  }
  float o = 0.f; d = 0.f;
  #pragma unroll
  for (int r = 0; r < 8; ++r) {
    float v = vals[r], a2 = v - tau;
    if (a2 > 0.f) o += v * a2;
  }
  bred2(o, d, tid, red);
  if (tid == 0) *outp = o;
}

__global__ __launch_bounds__(256) void hcam_fused_bf(
    const u16* __restrict__ A, const u16* __restrict__ B,
    const int* __restrict__ ilen, const int* __restrict__ clen, float* __restrict__ out) {
  const int b = blockIdx.x;
  const int i = b >> 7, t = b & 127;
  const int tid = threadIdx.x;
  const int il = ilen[i], cl = clen[t];
  float vals[8];
  #pragma unroll
  for (int r = 0; r < 8; ++r) {
    int p = tid + (r << 8);
    float v = 0.f;
    if (p < NEL) {
      int k = p / LC, l = p - k * LC;
      if (k < il && l < cl) {
        const u16* ar = A + (size_t)(i * KI + k) * DD;
        const u16* br = B + (size_t)(t * LC + l) * DD;
        float s = 0.f;
        for (int dd = 0; dd < DD; dd += 8) {
          u16x8 av = *(const u16x8*)(ar + dd);
          u16x8 bv = *(const u16x8*)(br + dd);
          #pragma unroll
          for (int q = 0; q < 8; ++q) s += bf2f(av[q]) * bf2f(bv[q]);
        }
        v = s;
      }
    }
    vals[r] = v;
  }
  __shared__ float red[8];
  sparsemax_out(vals, tid, red, &out[b]);
}

__global__ __launch_bounds__(256) void hcam_fused_raw(
    const float* __restrict__ imgs, const float* __restrict__ caps,
    const int* __restrict__ ilen, const int* __restrict__ clen, float* __restrict__ out) {
  const int b = blockIdx.x;
  const int i = b >> 7, t = b & 127;
  const int tid = threadIdx.x;
  const int w = tid >> 6, lane = tid & 63;
  __shared__ float inv[KI + LC];
  for (int row = w; row < KI + LC; row += 4) {
    const float* src = (row < KI) ? imgs + (size_t)(i * KI + row) * DD
                                  : caps + (size_t)(t * LC + (row - KI)) * DD;
    float ss = 0.f;
    for (int e = lane; e < DD; e += 64) { float x = src[e] + EPSF; ss += x * x; }
    #pragma unroll
    for (int m = 32; m; m >>= 1) ss += __shfl_xor(ss, m);
    if (lane == 0) inv[row] = 1.0f / sqrtf(ss);
  }
  __syncthreads();
  const int il = ilen[i], cl = clen[t];
  float vals[8];
  #pragma unroll
  for (int r = 0; r < 8; ++r) {
    int p = tid + (r << 8);
    float v = 0.f;
    if (p < NEL) {
      int k = p / LC, l = p - k * LC;
      if (k < il && l < cl) {
        const float* ar = imgs + (size_t)(i * KI + k) * DD;
        const float* br = caps + (size_t)(t * LC + l) * DD;
        float s = 0.f;
        for (int dd = 0; dd < DD; dd += 4) {
          float4 a4 = *(const float4*)(ar + dd);
          float4 b4 = *(const float4*)(br + dd);
          s += (a4.x + EPSF) * (b4.x + EPSF) + (a4.y + EPSF) * (b4.y + EPSF)
             + (a4.z + EPSF) * (b4.z + EPSF) + (a4.w + EPSF) * (b4.w + EPSF);
        }
        v = s * inv[k] * inv[KI + l];
      }
    }
    vals[r] = v;
  }
  __shared__ float red[8];
  sparsemax_out(vals, tid, red, &out[b]);
}

extern "C" void kernel_launch(void* const* d_in, const int* in_sizes, int n_in,
                              void* d_out, int out_size, void* d_ws, size_t ws_size,
                              hipStream_t stream) {
  (void)in_sizes; (void)n_in; (void)out_size;
  const float* imgs = (const float*)d_in[1];
  const float* caps = (const float*)d_in[3];
  const int*   ilen = (const int*)d_in[4];
  const int*   clen = (const int*)d_in[5];
  float* out = (float*)d_out;

  const size_t offB     = (size_t)GM * DD * sizeof(u16);
  const size_t offC     = offB + (size_t)GN * DD * sizeof(u16);
  const size_t needFull = offC + (size_t)GM * GN * sizeof(_Float16);
  u16*      A = (u16*)d_ws;
  u16*      B = (u16*)((char*)d_ws + offB);
  _Float16* C = (_Float16*)((char*)d_ws + offC);

  if (ws_size >= needFull) {
    hcam_normcast<<<dim3(GM + GN), dim3(256), 0, stream>>>(imgs, caps, A, B);
    hcam_gemm128d<<<dim3(MT * NT), dim3(256), 0, stream>>>(A, B, C);
    hcam_spmax_w<<<dim3(NBI * NBT / 4), dim3(256), 0, stream>>>(C, ilen, clen, out);
  } else if (ws_size >= offC) {
    hcam_normcast<<<dim3(GM + GN), dim3(256), 0, stream>>>(imgs, caps, A, B);
    hcam_fused_bf<<<dim3(NBI * NBT), dim3(256), 0, stream>>>(A, B, ilen, clen, out);
  } else {
    hcam_fused_raw<<<dim3(NBI * NBT), dim3(256), 0, stream>>>(imgs, caps, ilen, clen, out);
  }
}